// Round 20
// baseline (709.121 us; speedup 1.0000x reference)
//
#include <hip/hip_runtime.h>
#include <hip/hip_bf16.h>
#include <hip/hip_cooperative_groups.h>

namespace cg = cooperative_groups;

// DimeNet-like GNN, f32 in/out. Round 19: coop retry with SAFETY NET.
// r18's all-zero (absmax==140) means hipLaunchCooperativeKernel rejected the
// launch and the error was unchecked. Now: k_all uses __launch_bounds__(256,2)
// + grid<=512 (round-9-proven coop config), host CHECKS the launch result and
// falls back to the r17 9-dispatch path (314us, passing) on any error.

#define N_NODES 16000
#define N_EDGES 256000
#define N_TRI   640000
#define N_B     128
#define OUT_DIM 32
#define L_LAYERS 3

typedef __hip_bfloat16 bf16;
typedef short s8v __attribute__((ext_vector_type(8)));
typedef float f4v __attribute__((ext_vector_type(4)));

#define NTS(p, v) __builtin_nontemporal_store((v), (p))

__device__ __forceinline__ unsigned short f2bf_rne(float x) {
    unsigned int u = __float_as_uint(x);
    unsigned int r = (u + 0x7FFFu + ((u >> 16) & 1u)) >> 16;
    return (unsigned short)r;
}
__device__ __forceinline__ float bf2f(unsigned short b) {
    return __uint_as_float(((unsigned int)b) << 16);
}
__device__ __forceinline__ void split2(float a, unsigned short& h, unsigned short& l) {
    h = f2bf_rne(a);
    l = f2bf_rne(a - bf2f(h));
}
__device__ __forceinline__ void make_afrag(const float* av, s8v& ah, s8v& al) {
    #pragma unroll
    for (int j = 0; j < 8; j++) {
        unsigned short h, l; split2(av[j], h, l);
        ah[j] = (short)h; al[j] = (short)l;
    }
}

__device__ __forceinline__ void ldbfrag(const float* W, int ks, int nt,
                                        int lane, s8v& bh, s8v& bl) {
    int k0 = ks * 32 + ((lane >> 4) & 3) * 8;
    int n = nt * 16 + (lane & 15);
    float wv[8];
    #pragma unroll
    for (int j = 0; j < 8; j++)
        wv[j] = W[(size_t)(k0 + j) * 64 + n];
    make_afrag(wv, bh, bl);
}

__device__ __forceinline__ void mfma1g(const float* W, int ks, int nt, int lane,
                                       const s8v& ah, const s8v& al, f4v& acc) {
    s8v bh, bl;
    ldbfrag(W, ks, nt, lane, bh, bl);
    acc = __builtin_amdgcn_mfma_f32_16x16x32_bf16(ah, bh, acc, 0, 0, 0);
    acc = __builtin_amdgcn_mfma_f32_16x16x32_bf16(al, bh, acc, 0, 0, 0);
    acc = __builtin_amdgcn_mfma_f32_16x16x32_bf16(ah, bl, acc, 0, 0, 0);
}

__device__ __forceinline__ void ldrow8f(const float* A, size_t row, int ks,
                                        int quad, float av[8]) {
    const float* p = A + row * 64 + ks * 32 + quad * 8;
    float4 x0 = ((const float4*)p)[0], x1 = ((const float4*)p)[1];
    av[0] = x0.x; av[1] = x0.y; av[2] = x0.z; av[3] = x0.w;
    av[4] = x1.x; av[5] = x1.y; av[6] = x1.z; av[7] = x1.w;
}

// ---------------------------------------------------------------- shared device bodies
struct LayerP {
    const int *ends_t, *tri_o, *k_srt, *ends_e, *src_s;
    const float *X, *Y, *rbf, *cbf, *A1;
    const float *W1l, *W2a, *Wn1l, *bn1l, *Wn2l, *bn2l;
    const float *W1n, *b1n, *W2n, *b2n;
    float *hout, *Xn, *Yn;
    int has_next;
};

// one 16-node tile of the fused layer; needs sA/sB (16*68 floats each)
__device__ void meg_tile(const LayerP& g, int bb, float* sA, float* sB) {
    const int lane = threadIdx.x & 63;
    const int w = threadIdx.x >> 6;
    const int quad = lane >> 4;
    const int m = lane & 15;
    const size_t row = (size_t)bb * 16 + m;
    float av[8]; s8v ah, al;

    // Phase T: tri buckets (4/wave) -> sA
    {
        int nb = bb * 16 + w * 4;
        int q0 = (nb == 0) ? 0 : g.ends_t[nb - 1];
        int e1 = g.ends_t[nb], e2 = g.ends_t[nb + 1];
        int e3 = g.ends_t[nb + 2], q1 = g.ends_t[nb + 3];
        if (q0 < 0) q0 = 0; if (q0 > N_TRI) q0 = N_TRI;
        if (q1 < q0) q1 = q0; if (q1 > N_TRI) q1 = N_TRI;
        if (e1 < q0) e1 = q0; if (e1 > q1) e1 = q1;
        if (e2 < e1) e2 = e1; if (e2 > q1) e2 = q1;
        if (e3 < e2) e3 = e2; if (e3 > q1) e3 = q1;
        float wr[6], wc[6];
        #pragma unroll
        for (int q = 0; q < 6; q++) {
            wr[q] = g.W1l[(size_t)(64 + q) * 64 + lane];
            wc[q] = g.W1l[(size_t)(70 + q) * 64 + lane];
        }
        float rb[4];
        #pragma unroll
        for (int i = 0; i < 4; i++) {
            float r = 0.f;
            #pragma unroll
            for (int q = 0; q < 6; q++)
                r += g.rbf[(size_t)(nb + i) * 6 + q] * wr[q];
            rb[i] = r;
        }
        float s0 = 0.f, s1 = 0.f, s2 = 0.f, s3 = 0.f;
        for (int p = q0; p < q1; p += 4) {
            int tq[4], kq[4];
            float hv[4], cb[4][6];
            #pragma unroll
            for (int i = 0; i < 4; i++) {
                int ok = (p + i < q1);
                int t = ok ? g.tri_o[p + i] : -1;
                if ((unsigned)t >= N_TRI) t = -1;
                tq[i] = t;
                int k = ok ? g.k_srt[p + i] : 0;
                if ((unsigned)k >= N_NODES) k = 0;
                kq[i] = k;
            }
            #pragma unroll
            for (int i = 0; i < 4; i++)
                hv[i] = g.X[(size_t)kq[i] * 64 + lane];
            #pragma unroll
            for (int i = 0; i < 4; i++) {
                if (tq[i] >= 0) {
                    const float2* cp = (const float2*)(g.cbf + (size_t)tq[i] * 6);
                    float2 c0 = cp[0], c1 = cp[1], c2 = cp[2];
                    cb[i][0] = c0.x; cb[i][1] = c0.y; cb[i][2] = c1.x;
                    cb[i][3] = c1.y; cb[i][4] = c2.x; cb[i][5] = c2.y;
                }
            }
            #pragma unroll
            for (int i = 0; i < 4; i++) {
                int pp = p + i;
                if (tq[i] < 0) continue;
                float rbv = (pp >= e3) ? rb[3] : (pp >= e2) ? rb[2] : (pp >= e1) ? rb[1] : rb[0];
                float v = hv[i] + rbv;
                #pragma unroll
                for (int q = 0; q < 6; q++)
                    v += cb[i][q] * wc[q];
                v = fmaxf(v, 0.f);
                if (pp < e1) s0 += v;
                else if (pp < e2) s1 += v;
                else if (pp < e3) s2 += v;
                else s3 += v;
            }
        }
        sA[(w * 4 + 0) * 68 + lane] = s0;
        sA[(w * 4 + 1) * 68 + lane] = s1;
        sA[(w * 4 + 2) * 68 + lane] = s2;
        sA[(w * 4 + 3) * 68 + lane] = s3;
    }
    __syncthreads();

    // Phase A: Ad = sA @ W2a -> sB
    {
        f4v acc = (f4v){0.f, 0.f, 0.f, 0.f};
        #pragma unroll
        for (int ks = 0; ks < 2; ks++) {
            #pragma unroll
            for (int j = 0; j < 8; j++)
                av[j] = sA[m * 68 + ks * 32 + quad * 8 + j];
            make_afrag(av, ah, al);
            mfma1g(g.W2a, ks, w, lane, ah, al, acc);
        }
        #pragma unroll
        for (int r = 0; r < 4; r++)
            sB[(quad * 4 + r) * 68 + w * 16 + m] = acc[r];
    }
    __syncthreads();

    // Phase B: edge buckets (4/wave) -> sA
    {
        int dbase = bb * 16 + w * 4;
        int q0 = (dbase == 0) ? 0 : g.ends_e[dbase - 1];
        int e1 = g.ends_e[dbase], e2 = g.ends_e[dbase + 1];
        int e3 = g.ends_e[dbase + 2], q1 = g.ends_e[dbase + 3];
        if (q0 < 0) q0 = 0; if (q0 > N_EDGES) q0 = N_EDGES;
        if (q1 < q0) q1 = q0; if (q1 > N_EDGES) q1 = N_EDGES;
        if (e1 < q0) e1 = q0; if (e1 > q1) e1 = q1;
        if (e2 < e1) e2 = e1; if (e2 > q1) e2 = q1;
        if (e3 < e2) e3 = e2; if (e3 > q1) e3 = q1;
        float ad0 = sB[(w * 4 + 0) * 68 + lane];
        float ad1 = sB[(w * 4 + 1) * 68 + lane];
        float ad2 = sB[(w * 4 + 2) * 68 + lane];
        float ad3 = sB[(w * 4 + 3) * 68 + lane];
        float s0 = 0.f, s1 = 0.f, s2 = 0.f, s3 = 0.f;
        for (int p = q0; p < q1; p += 8) {
            int ss[8]; float hv[8];
            #pragma unroll
            for (int i = 0; i < 8; i++) {
                int sv = (p + i < q1) ? g.src_s[p + i] : 0;
                if ((unsigned)sv >= N_NODES) sv = 0;
                ss[i] = sv;
            }
            #pragma unroll
            for (int i = 0; i < 8; i++)
                hv[i] = g.Y[(size_t)ss[i] * 64 + lane];
            #pragma unroll
            for (int i = 0; i < 8; i++) {
                int pp = p + i;
                if (pp >= q1) continue;
                float ad = (pp >= e3) ? ad3 : (pp >= e2) ? ad2 : (pp >= e1) ? ad1 : ad0;
                float v = fmaxf(hv[i] + ad, 0.f);
                if (pp < e1) s0 += v;
                else if (pp < e2) s1 += v;
                else if (pp < e3) s2 += v;
                else s3 += v;
            }
        }
        sA[(w * 4 + 0) * 68 + lane] = s0;
        sA[(w * 4 + 1) * 68 + lane] = s1;
        sA[(w * 4 + 2) * 68 + lane] = s2;
        sA[(w * 4 + 3) * 68 + lane] = s3;
    }
    __syncthreads();

    // Phase C1: z = relu([A1 | aggr] @ Wn1 + bn1) -> sB
    {
        float b = g.bn1l[w * 16 + m];
        f4v acc = (f4v){b, b, b, b};
        #pragma unroll
        for (int ks = 0; ks < 2; ks++) {
            ldrow8f(g.A1, row, ks, quad, av);
            make_afrag(av, ah, al);
            mfma1g(g.Wn1l, ks, w, lane, ah, al, acc);
        }
        #pragma unroll
        for (int ks = 0; ks < 2; ks++) {
            #pragma unroll
            for (int j = 0; j < 8; j++)
                av[j] = sA[m * 68 + ks * 32 + quad * 8 + j];
            make_afrag(av, ah, al);
            mfma1g(g.Wn1l + 64 * 64, ks, w, lane, ah, al, acc);
        }
        #pragma unroll
        for (int r = 0; r < 4; r++)
            sB[(quad * 4 + r) * 68 + w * 16 + m] = fmaxf(acc[r], 0.f);
    }
    __syncthreads();

    // Phase C2: h' = z @ Wn2 + bn2 -> global (+ next XY)
    f4v acc2;
    {
        float b = g.bn2l[w * 16 + m];
        acc2 = (f4v){b, b, b, b};
        #pragma unroll
        for (int ks = 0; ks < 2; ks++) {
            #pragma unroll
            for (int j = 0; j < 8; j++)
                av[j] = sB[m * 68 + ks * 32 + quad * 8 + j];
            make_afrag(av, ah, al);
            mfma1g(g.Wn2l, ks, w, lane, ah, al, acc2);
        }
        #pragma unroll
        for (int r = 0; r < 4; r++)
            NTS(&g.hout[(size_t)(bb * 16 + quad * 4 + r) * 64 + w * 16 + m], acc2[r]);
    }
    if (g.has_next) {
        __syncthreads();
        #pragma unroll
        for (int r = 0; r < 4; r++)
            sA[(quad * 4 + r) * 68 + w * 16 + m] = acc2[r];
        __syncthreads();
        float bx = g.b1n[w * 16 + m];
        float by = g.b2n[w * 16 + m];
        f4v aX = (f4v){bx, bx, bx, bx};
        f4v aY = (f4v){by, by, by, by};
        #pragma unroll
        for (int ks = 0; ks < 2; ks++) {
            #pragma unroll
            for (int j = 0; j < 8; j++)
                av[j] = sA[m * 68 + ks * 32 + quad * 8 + j];
            make_afrag(av, ah, al);
            mfma1g(g.W1n, ks, w, lane, ah, al, aX);
            mfma1g(g.W2n, ks, w, lane, ah, al, aY);
        }
        #pragma unroll
        for (int r = 0; r < 4; r++) {
            size_t rr = (size_t)(bb * 16 + quad * 4 + r) * 64 + w * 16 + m;
            NTS(&g.Xn[rr], aX[r]);
            NTS(&g.Yn[rr], aY[r]);
        }
    }
}

__device__ void lin2out_tile(const float* x, const float* W1, const float* b1,
                             const float* W2, const float* b2,
                             float* X, float* Y, int tile) {
    const int lane = threadIdx.x & 63;
    const int w = threadIdx.x >> 6;
    const int quad = lane >> 4;
    const int m = lane & 15;
    size_t row = (size_t)tile * 16 + m;
    float bx = b1[w * 16 + m];
    float by = b2[w * 16 + m];
    f4v aX = (f4v){bx, bx, bx, bx};
    f4v aY = (f4v){by, by, by, by};
    float av[8]; s8v ah, al;
    #pragma unroll
    for (int ks = 0; ks < 2; ks++) {
        ldrow8f(x, row, ks, quad, av);
        make_afrag(av, ah, al);
        mfma1g(W1, ks, w, lane, ah, al, aX);
        mfma1g(W2, ks, w, lane, ah, al, aY);
    }
    #pragma unroll
    for (int r = 0; r < 4; r++) {
        size_t rr = (size_t)(tile * 16 + quad * 4 + r) * 64 + w * 16 + m;
        NTS(&X[rr], aX[r]);
        NTS(&Y[rr], aY[r]);
    }
}

__device__ void poolhead_graph(const float* h, const int* batch,
                               const float* Wo1, const float* bo1,
                               const float* Wo2, const float* bo2,
                               float* out, int b, float* red) {
    const int lane = threadIdx.x & 63;
    const int w = threadIdx.x >> 6;
    int lo = 0, hi = N_NODES;
    while (lo < hi) { int mid = (lo + hi) >> 1; if (batch[mid] < b) lo = mid + 1; else hi = mid; }
    int start = lo;
    hi = N_NODES;
    while (lo < hi) { int mid = (lo + hi) >> 1; if (batch[mid] < b + 1) lo = mid + 1; else hi = mid; }
    int end = lo;
    float s = 0.f;
    for (int n = start + w; n < end; n += 4)
        s += h[(size_t)n * 64 + lane];
    red[w * 64 + lane] = s;
    __syncthreads();
    if (w == 0) {
        float tot = red[lane] + red[64 + lane] + red[128 + lane] + red[192 + lane];
        float c = (float)(end - start);
        float p = fmaxf(tot / fmaxf(c, 1.0f), 0.f);
        float acc = bo1[lane];
        #pragma unroll
        for (int kk = 0; kk < 64; kk++)
            acc += __shfl(p, kk) * Wo1[kk * 64 + lane];
        float t1 = fmaxf(acc, 0.f);
        float acc2 = (lane < OUT_DIM) ? bo2[lane] : 0.f;
        #pragma unroll
        for (int kk = 0; kk < 64; kk++) {
            float wv = (lane < OUT_DIM) ? Wo2[kk * OUT_DIM + lane] : 0.f;
            acc2 += __shfl(t1, kk) * wv;
        }
        if (lane < OUT_DIM) out[b * OUT_DIM + lane] = acc2;
    }
    __syncthreads();
}

// ---------------------------------------------------------------- diag
__global__ void k_fill(float* __restrict__ out, float val, int n) {
    int i = blockIdx.x * blockDim.x + threadIdx.x;
    if (i < n) out[i] = val;
}

// ---------------------------------------------------------------- r17 kernels (fallback path)
__global__ void k_setup(int* __restrict__ cur) {
    int i = blockIdx.x * blockDim.x + threadIdx.x;
    int stride = gridDim.x * blockDim.x;
    for (; i < 2 * N_NODES; i += stride) cur[i] = 0;
}

__global__ void k_hist2(const int* __restrict__ j_idx, const int* __restrict__ edge_index,
                        int* __restrict__ cur_t, int* __restrict__ cur_e) {
    const int TB = (N_TRI + 255) / 256;
    if ((int)blockIdx.x < TB) {
        int i = blockIdx.x * 256 + threadIdx.x;
        if (i < N_TRI) {
            unsigned j = (unsigned)j_idx[i];
            if (j < N_NODES) atomicAdd(&cur_t[j], 1);
        }
    } else {
        int i = (blockIdx.x - TB) * 256 + threadIdx.x;
        if (i < N_EDGES) {
            unsigned d = (unsigned)edge_index[N_EDGES + i];
            if (d < N_NODES) atomicAdd(&cur_e[d], 1);
        }
    }
}

__global__ __launch_bounds__(256) void k_scan2(int* __restrict__ a, int* __restrict__ b) {
    int* cnt = (blockIdx.x == 0) ? a : b;
    __shared__ int part[256];
    int tid = threadIdx.x;
    const int PER = (N_NODES + 255) / 256;
    int base = tid * PER;
    int s = 0;
    for (int i = 0; i < PER; i++) {
        int idx = base + i;
        if (idx < N_NODES) s += cnt[idx];
    }
    part[tid] = s;
    __syncthreads();
    for (int d = 1; d < 256; d <<= 1) {
        int v = (tid >= d) ? part[tid - d] : 0;
        __syncthreads();
        part[tid] += v;
        __syncthreads();
    }
    int run = (tid > 0) ? part[tid - 1] : 0;
    for (int i = 0; i < PER; i++) {
        int idx = base + i;
        if (idx < N_NODES) {
            int v = cnt[idx];
            cnt[idx] = run;
            run += v;
        }
    }
}

__global__ void k_scatter2(const int* __restrict__ j_idx, const int* __restrict__ k_idx,
                           const int* __restrict__ edge_index,
                           int* __restrict__ cur_t, int* __restrict__ cur_e,
                           int* __restrict__ tri_o, int* __restrict__ k_srt,
                           int* __restrict__ src_s) {
    const int TB = (N_TRI + 255) / 256;
    if ((int)blockIdx.x < TB) {
        int i = blockIdx.x * 256 + threadIdx.x;
        if (i < N_TRI) {
            unsigned j = (unsigned)j_idx[i];
            if (j < N_NODES) {
                int pos = atomicAdd(&cur_t[j], 1);
                if ((unsigned)pos < (unsigned)N_TRI) {
                    unsigned k = (unsigned)k_idx[i]; if (k >= N_NODES) k = 0;
                    tri_o[pos] = i;
                    k_srt[pos] = (int)k;
                }
            }
        }
    } else {
        int e = (blockIdx.x - TB) * 256 + threadIdx.x;
        if (e < N_EDGES) {
            unsigned d = (unsigned)edge_index[N_EDGES + e];
            if (d < N_NODES) {
                int pos = atomicAdd(&cur_e[d], 1);
                if ((unsigned)pos < (unsigned)N_EDGES) {
                    unsigned s = (unsigned)edge_index[e]; if (s >= N_NODES) s = 0;
                    src_s[pos] = (int)s;
                }
            }
        }
    }
}

__global__ __launch_bounds__(256) void k_lin2out(
    const float* __restrict__ x,
    const float* __restrict__ W1, const float* __restrict__ b1,
    const float* __restrict__ W2, const float* __restrict__ b2,
    float* __restrict__ X, float* __restrict__ Y) {
    lin2out_tile(x, W1, b1, W2, b2, X, Y, blockIdx.x);
}

__global__ __launch_bounds__(256) void k_meg(LayerP g) {
    __shared__ float sA[16 * 68];
    __shared__ float sB[16 * 68];
    meg_tile(g, blockIdx.x, sA, sB);
}

__global__ __launch_bounds__(256) void k_poolhead(
    const float* __restrict__ h, const int* __restrict__ batch,
    const float* __restrict__ Wo1, const float* __restrict__ bo1,
    const float* __restrict__ Wo2, const float* __restrict__ bo2,
    float* __restrict__ out) {
    __shared__ float red[4 * 64];
    poolhead_graph(h, batch, Wo1, bo1, Wo2, bo2, out, blockIdx.x, red);
}

// ---------------------------------------------------------------- coop kernel
struct AllA {
    const int *j_idx, *k_idx, *edge_index, *batch;
    const float *x, *rbf, *cbf;
    const float *W1, *b1, *W2, *b2, *Wn1, *bn1, *Wn2, *bn2;
    const float *Wo1, *bo1, *Wo2, *bo2;
    int *cur_t, *cur_e, *tri_o, *k_srt, *src_s;
    float *hA, *hB, *X0, *Y0, *X1, *Y1;
    float *out;
};

__global__ __launch_bounds__(256, 2) void k_all(AllA a) {
    cg::grid_group gg = cg::this_grid();
    __shared__ float sA[16 * 68];
    __shared__ float sB[16 * 68];
    __shared__ int part[256];
    const int tid = threadIdx.x;
    const int gthr = blockIdx.x * 256 + tid;
    const int nthr = gridDim.x * 256;
    const int NTILE = N_NODES / 16;

    // P0: zero cursors + layer-0 lin2out
    for (int i = gthr; i < 2 * N_NODES; i += nthr) a.cur_t[i] = 0;
    for (int tile = blockIdx.x; tile < NTILE; tile += gridDim.x)
        lin2out_tile(a.x, a.W1, a.b1, a.W2, a.b2, a.X0, a.Y0, tile);
    gg.sync();

    // P1: histograms
    for (int i = gthr; i < N_TRI; i += nthr) {
        unsigned j = (unsigned)a.j_idx[i];
        if (j < N_NODES) atomicAdd(&a.cur_t[j], 1);
    }
    for (int i = gthr; i < N_EDGES; i += nthr) {
        unsigned d = (unsigned)a.edge_index[N_EDGES + i];
        if (d < N_NODES) atomicAdd(&a.cur_e[d], 1);
    }
    gg.sync();

    // P2: scans (blocks 0,1)
    if (blockIdx.x < 2) {
        int* cnt = (blockIdx.x == 0) ? a.cur_t : a.cur_e;
        const int PER = (N_NODES + 255) / 256;
        int base = tid * PER;
        int s = 0;
        for (int i = 0; i < PER; i++) {
            int idx = base + i;
            if (idx < N_NODES) s += cnt[idx];
        }
        part[tid] = s;
        __syncthreads();
        for (int d = 1; d < 256; d <<= 1) {
            int v = (tid >= d) ? part[tid - d] : 0;
            __syncthreads();
            part[tid] += v;
            __syncthreads();
        }
        int run = (tid > 0) ? part[tid - 1] : 0;
        for (int i = 0; i < PER; i++) {
            int idx = base + i;
            if (idx < N_NODES) {
                int v = cnt[idx];
                cnt[idx] = run;
                run += v;
            }
        }
    }
    gg.sync();

    // P3: scatter + payloads
    for (int i = gthr; i < N_TRI; i += nthr) {
        unsigned j = (unsigned)a.j_idx[i];
        if (j < N_NODES) {
            int pos = atomicAdd(&a.cur_t[j], 1);
            if ((unsigned)pos < (unsigned)N_TRI) {
                unsigned k = (unsigned)a.k_idx[i]; if (k >= N_NODES) k = 0;
                a.tri_o[pos] = i;
                a.k_srt[pos] = (int)k;
            }
        }
    }
    for (int e = gthr; e < N_EDGES; e += nthr) {
        unsigned d = (unsigned)a.edge_index[N_EDGES + e];
        if (d < N_NODES) {
            int pos = atomicAdd(&a.cur_e[d], 1);
            if ((unsigned)pos < (unsigned)N_EDGES) {
                unsigned s = (unsigned)a.edge_index[e]; if (s >= N_NODES) s = 0;
                a.src_s[pos] = (int)s;
            }
        }
    }
    gg.sync();

    // layers
    for (int l = 0; l < L_LAYERS; l++) {
        LayerP g;
        g.ends_t = a.cur_t; g.tri_o = a.tri_o; g.k_srt = a.k_srt;
        g.ends_e = a.cur_e; g.src_s = a.src_s;
        g.X = (l == 1) ? a.X1 : a.X0;
        g.Y = (l == 1) ? a.Y1 : a.Y0;
        g.rbf = a.rbf; g.cbf = a.cbf;
        g.A1 = (l == 0) ? a.x : ((l == 1) ? a.hA : a.hB);
        g.W1l  = a.W1 + (size_t)l * 76 * 64;
        g.W2a  = a.W2 + (size_t)l * 128 * 64 + 64 * 64;
        g.Wn1l = a.Wn1 + (size_t)l * 128 * 64;
        g.bn1l = a.bn1 + (size_t)l * 64;
        g.Wn2l = a.Wn2 + (size_t)l * 64 * 64;
        g.bn2l = a.bn2 + (size_t)l * 64;
        g.has_next = (l < L_LAYERS - 1);
        g.W1n = a.W1 + (size_t)(l + 1) * 76 * 64;
        g.b1n = a.b1 + (size_t)(l + 1) * 64;
        g.W2n = a.W2 + (size_t)(l + 1) * 128 * 64;
        g.b2n = a.b2 + (size_t)(l + 1) * 64;
        g.hout = (l == 1) ? a.hB : a.hA;
        g.Xn = (l == 0) ? a.X1 : a.X0;
        g.Yn = (l == 0) ? a.Y1 : a.Y0;
        for (int bb = blockIdx.x; bb < NTILE; bb += gridDim.x) {
            meg_tile(g, bb, sA, sB);
            __syncthreads();
        }
        gg.sync();
    }

    // poolhead
    for (int b = blockIdx.x; b < N_B; b += gridDim.x)
        poolhead_graph(a.hA, a.batch, a.Wo1, a.bo1, a.Wo2, a.bo2, a.out, b, sA);
}

extern "C" void kernel_launch(void* const* d_in, const int* in_sizes, int n_in,
                              void* d_out, int out_size, void* d_ws, size_t ws_size,
                              hipStream_t stream) {
    const int expect[19] = {
        N_NODES * 64, N_EDGES * 6, N_TRI * 6,
        L_LAYERS * 76 * 64, L_LAYERS * 64,
        L_LAYERS * 128 * 64, L_LAYERS * 64,
        L_LAYERS * 128 * 64, L_LAYERS * 64,
        L_LAYERS * 64 * 64, L_LAYERS * 64,
        64 * 64, 64, 64 * OUT_DIM, OUT_DIM,
        2 * N_EDGES, N_TRI, N_TRI, N_NODES
    };

    char* ws = (char*)d_ws;
    float* hA    = (float*)(ws + 0);
    float* hB    = (float*)(ws + 4096000);
    float* X0    = (float*)(ws + 8192000);
    float* Y0    = (float*)(ws + 12288000);
    float* X1    = (float*)(ws + 16384000);
    float* Y1    = (float*)(ws + 20480000);
    int*   cur_t = (int*)(ws + 24576000);
    int*   cur_e = (int*)(ws + 24640000);
    int*   tri_o = (int*)(ws + 24704000);
    int*   k_srt = (int*)(ws + 27264000);
    int*   src_s = (int*)(ws + 29824000);
    const size_t FULL_NEED = 30848000u;

    const int out_n = N_B * OUT_DIM;

    int perm[19];
    bool used[64];
    for (int i = 0; i < 64; i++) used[i] = false;
    int fail_slot = -1;
    for (int i = 0; i < 19; i++) {
        perm[i] = -1;
        for (int jj = 0; jj < n_in && jj < 64; jj++) {
            if (!used[jj] && in_sizes[jj] == expect[i]) { used[jj] = true; perm[i] = jj; break; }
        }
        if (perm[i] < 0 && fail_slot < 0) fail_slot = i;
    }

    if (n_in < 19 || fail_slot >= 0 || ws_size < FULL_NEED) {
        float code = (ws_size < FULL_NEED) ? 40000.0f
                   : (n_in < 19)           ? 50000.0f
                   : 20000.0f + 1000.0f * (float)fail_slot;
        k_fill<<<(out_n + 255) / 256, 256, 0, stream>>>((float*)d_out, code, out_n);
        return;
    }

    AllA a;
    a.x   = (const float*)d_in[perm[0]];
    a.rbf = (const float*)d_in[perm[1]];
    a.cbf = (const float*)d_in[perm[2]];
    a.W1  = (const float*)d_in[perm[3]];
    a.b1  = (const float*)d_in[perm[4]];
    a.W2  = (const float*)d_in[perm[5]];
    a.b2  = (const float*)d_in[perm[6]];
    a.Wn1 = (const float*)d_in[perm[7]];
    a.bn1 = (const float*)d_in[perm[8]];
    a.Wn2 = (const float*)d_in[perm[9]];
    a.bn2 = (const float*)d_in[perm[10]];
    a.Wo1 = (const float*)d_in[perm[11]];
    a.bo1 = (const float*)d_in[perm[12]];
    a.Wo2 = (const float*)d_in[perm[13]];
    a.bo2 = (const float*)d_in[perm[14]];
    a.edge_index = (const int*)d_in[perm[15]];
    a.k_idx = (const int*)d_in[perm[16]];
    a.j_idx = (const int*)d_in[perm[17]];
    a.batch = (const int*)d_in[perm[18]];
    a.cur_t = cur_t; a.cur_e = cur_e;
    a.tri_o = tri_o; a.k_srt = k_srt; a.src_s = src_s;
    a.hA = hA; a.hB = hB;
    a.X0 = X0; a.Y0 = Y0; a.X1 = X1; a.Y1 = Y1;
    a.out = (float*)d_out;

    // ---- try the single cooperative kernel (grid <= 512, r9-proven size) ----
    int nb = 0;
    hipError_t oe = hipOccupancyMaxActiveBlocksPerMultiprocessor(&nb, k_all, 256, 0);
    if (oe != hipSuccess || nb < 1) nb = 1;
    int grid = nb * 256;
    if (grid > 512) grid = 512;
    if (grid < 2) grid = 2;
    void* args[] = {(void*)&a};
    hipError_t err = hipLaunchCooperativeKernel((void*)k_all, dim3(grid), dim3(256),
                                                args, 0, stream);
    if (err == hipSuccess) return;

    // ---- fallback: r17 9-dispatch path (known-good, 314us) ----
    const int TB = (N_TRI + 255) / 256;
    const int EB = (N_EDGES + 255) / 256;
    k_setup<<<64, 256, 0, stream>>>(cur_t);
    k_hist2<<<TB + EB, 256, 0, stream>>>(a.j_idx, a.edge_index, cur_t, cur_e);
    k_scan2<<<2, 256, 0, stream>>>(cur_t, cur_e);
    k_scatter2<<<TB + EB, 256, 0, stream>>>(a.j_idx, a.k_idx, a.edge_index,
                                            cur_t, cur_e, tri_o, k_srt, src_s);
    k_lin2out<<<N_NODES / 16, 256, 0, stream>>>(a.x, a.W1, a.b1, a.W2, a.b2, X0, Y0);

    const float* hc = a.x;
    float* hout = hA;
    float* Xc = X0; float* Yc = Y0;
    float* Xn = X1; float* Yn = Y1;
    for (int l = 0; l < L_LAYERS; l++) {
        LayerP g;
        g.ends_t = cur_t; g.tri_o = tri_o; g.k_srt = k_srt;
        g.ends_e = cur_e; g.src_s = src_s;
        g.X = Xc; g.Y = Yc;
        g.rbf = a.rbf; g.cbf = a.cbf; g.A1 = hc;
        g.W1l  = a.W1 + (size_t)l * 76 * 64;
        g.W2a  = a.W2 + (size_t)l * 128 * 64 + 64 * 64;
        g.Wn1l = a.Wn1 + (size_t)l * 128 * 64;
        g.bn1l = a.bn1 + (size_t)l * 64;
        g.Wn2l = a.Wn2 + (size_t)l * 64 * 64;
        g.bn2l = a.bn2 + (size_t)l * 64;
        g.has_next = (l < L_LAYERS - 1) ? 1 : 0;
        g.W1n = a.W1 + (size_t)(l + 1) * 76 * 64;
        g.b1n = a.b1 + (size_t)(l + 1) * 64;
        g.W2n = a.W2 + (size_t)(l + 1) * 128 * 64;
        g.b2n = a.b2 + (size_t)(l + 1) * 64;
        g.hout = hout; g.Xn = Xn; g.Yn = Yn;
        k_meg<<<N_NODES / 16, 256, 0, stream>>>(g);
        hc = hout;
        hout = (hout == hA) ? hB : hA;
        float* t;
        t = Xc; Xc = Xn; Xn = t;
        t = Yc; Yc = Yn; Yn = t;
    }
    k_poolhead<<<N_B, 256, 0, stream>>>(hA, a.batch, a.Wo1, a.bo1, a.Wo2, a.bo2,
                                        (float*)d_out);
}

// Round 21
// 320.029 us; speedup vs baseline: 2.2158x; 2.2158x over previous
//
#include <hip/hip_runtime.h>
#include <hip/hip_bf16.h>

// DimeNet-like GNN, f32 in/out. Round 20: FINAL shape. r19's coop experiment
// proved the mega-kernel loses more to the 512-block co-residency cap (+430us
// in streaming/layer phases) than it saves in dispatch gaps (-100us), so the
// multi-kernel r17 structure (314us) is correct. One parallelism-neutral merge
// remains: k_scatter2 and k_lin2out are independent (scatter needs the scan;
// lin2out needs only x + layer-0 weights) -> one dispatch, block-range split.
// 8 dispatches: setup, hist2, scan2, scatlin, 3x k_meg, poolhead.

#define N_NODES 16000
#define N_EDGES 256000
#define N_TRI   640000
#define N_B     128
#define OUT_DIM 32
#define L_LAYERS 3

typedef __hip_bfloat16 bf16;
typedef short s8v __attribute__((ext_vector_type(8)));
typedef float f4v __attribute__((ext_vector_type(4)));

#define NTS(p, v) __builtin_nontemporal_store((v), (p))

__device__ __forceinline__ unsigned short f2bf_rne(float x) {
    unsigned int u = __float_as_uint(x);
    unsigned int r = (u + 0x7FFFu + ((u >> 16) & 1u)) >> 16;
    return (unsigned short)r;
}
__device__ __forceinline__ float bf2f(unsigned short b) {
    return __uint_as_float(((unsigned int)b) << 16);
}
__device__ __forceinline__ void split2(float a, unsigned short& h, unsigned short& l) {
    h = f2bf_rne(a);
    l = f2bf_rne(a - bf2f(h));
}
__device__ __forceinline__ void make_afrag(const float* av, s8v& ah, s8v& al) {
    #pragma unroll
    for (int j = 0; j < 8; j++) {
        unsigned short h, l; split2(av[j], h, l);
        ah[j] = (short)h; al[j] = (short)l;
    }
}

__device__ __forceinline__ void ldbfrag(const float* W, int ks, int nt,
                                        int lane, s8v& bh, s8v& bl) {
    int k0 = ks * 32 + ((lane >> 4) & 3) * 8;
    int n = nt * 16 + (lane & 15);
    float wv[8];
    #pragma unroll
    for (int j = 0; j < 8; j++)
        wv[j] = W[(size_t)(k0 + j) * 64 + n];
    make_afrag(wv, bh, bl);
}

__device__ __forceinline__ void mfma1g(const float* W, int ks, int nt, int lane,
                                       const s8v& ah, const s8v& al, f4v& acc) {
    s8v bh, bl;
    ldbfrag(W, ks, nt, lane, bh, bl);
    acc = __builtin_amdgcn_mfma_f32_16x16x32_bf16(ah, bh, acc, 0, 0, 0);
    acc = __builtin_amdgcn_mfma_f32_16x16x32_bf16(al, bh, acc, 0, 0, 0);
    acc = __builtin_amdgcn_mfma_f32_16x16x32_bf16(ah, bl, acc, 0, 0, 0);
}

__device__ __forceinline__ void ldrow8f(const float* A, size_t row, int ks,
                                        int quad, float av[8]) {
    const float* p = A + row * 64 + ks * 32 + quad * 8;
    float4 x0 = ((const float4*)p)[0], x1 = ((const float4*)p)[1];
    av[0] = x0.x; av[1] = x0.y; av[2] = x0.z; av[3] = x0.w;
    av[4] = x1.x; av[5] = x1.y; av[6] = x1.z; av[7] = x1.w;
}

// ---------------------------------------------------------------- shared device bodies
struct LayerP {
    const int *ends_t, *tri_o, *k_srt, *ends_e, *src_s;
    const float *X, *Y, *rbf, *cbf, *A1;
    const float *W1l, *W2a, *Wn1l, *bn1l, *Wn2l, *bn2l;
    const float *W1n, *b1n, *W2n, *b2n;
    float *hout, *Xn, *Yn;
    int has_next;
};

__device__ void meg_tile(const LayerP& g, int bb, float* sA, float* sB) {
    const int lane = threadIdx.x & 63;
    const int w = threadIdx.x >> 6;
    const int quad = lane >> 4;
    const int m = lane & 15;
    const size_t row = (size_t)bb * 16 + m;
    float av[8]; s8v ah, al;

    // Phase T: tri buckets (4/wave) -> sA
    {
        int nb = bb * 16 + w * 4;
        int q0 = (nb == 0) ? 0 : g.ends_t[nb - 1];
        int e1 = g.ends_t[nb], e2 = g.ends_t[nb + 1];
        int e3 = g.ends_t[nb + 2], q1 = g.ends_t[nb + 3];
        if (q0 < 0) q0 = 0; if (q0 > N_TRI) q0 = N_TRI;
        if (q1 < q0) q1 = q0; if (q1 > N_TRI) q1 = N_TRI;
        if (e1 < q0) e1 = q0; if (e1 > q1) e1 = q1;
        if (e2 < e1) e2 = e1; if (e2 > q1) e2 = q1;
        if (e3 < e2) e3 = e2; if (e3 > q1) e3 = q1;
        float wr[6], wc[6];
        #pragma unroll
        for (int q = 0; q < 6; q++) {
            wr[q] = g.W1l[(size_t)(64 + q) * 64 + lane];
            wc[q] = g.W1l[(size_t)(70 + q) * 64 + lane];
        }
        float rb[4];
        #pragma unroll
        for (int i = 0; i < 4; i++) {
            float r = 0.f;
            #pragma unroll
            for (int q = 0; q < 6; q++)
                r += g.rbf[(size_t)(nb + i) * 6 + q] * wr[q];
            rb[i] = r;
        }
        float s0 = 0.f, s1 = 0.f, s2 = 0.f, s3 = 0.f;
        for (int p = q0; p < q1; p += 4) {
            int tq[4], kq[4];
            float hv[4], cb[4][6];
            #pragma unroll
            for (int i = 0; i < 4; i++) {
                int ok = (p + i < q1);
                int t = ok ? g.tri_o[p + i] : -1;
                if ((unsigned)t >= N_TRI) t = -1;
                tq[i] = t;
                int k = ok ? g.k_srt[p + i] : 0;
                if ((unsigned)k >= N_NODES) k = 0;
                kq[i] = k;
            }
            #pragma unroll
            for (int i = 0; i < 4; i++)
                hv[i] = g.X[(size_t)kq[i] * 64 + lane];
            #pragma unroll
            for (int i = 0; i < 4; i++) {
                if (tq[i] >= 0) {
                    const float2* cp = (const float2*)(g.cbf + (size_t)tq[i] * 6);
                    float2 c0 = cp[0], c1 = cp[1], c2 = cp[2];
                    cb[i][0] = c0.x; cb[i][1] = c0.y; cb[i][2] = c1.x;
                    cb[i][3] = c1.y; cb[i][4] = c2.x; cb[i][5] = c2.y;
                }
            }
            #pragma unroll
            for (int i = 0; i < 4; i++) {
                int pp = p + i;
                if (tq[i] < 0) continue;
                float rbv = (pp >= e3) ? rb[3] : (pp >= e2) ? rb[2] : (pp >= e1) ? rb[1] : rb[0];
                float v = hv[i] + rbv;
                #pragma unroll
                for (int q = 0; q < 6; q++)
                    v += cb[i][q] * wc[q];
                v = fmaxf(v, 0.f);
                if (pp < e1) s0 += v;
                else if (pp < e2) s1 += v;
                else if (pp < e3) s2 += v;
                else s3 += v;
            }
        }
        sA[(w * 4 + 0) * 68 + lane] = s0;
        sA[(w * 4 + 1) * 68 + lane] = s1;
        sA[(w * 4 + 2) * 68 + lane] = s2;
        sA[(w * 4 + 3) * 68 + lane] = s3;
    }
    __syncthreads();

    // Phase A: Ad = sA @ W2a -> sB
    {
        f4v acc = (f4v){0.f, 0.f, 0.f, 0.f};
        #pragma unroll
        for (int ks = 0; ks < 2; ks++) {
            #pragma unroll
            for (int j = 0; j < 8; j++)
                av[j] = sA[m * 68 + ks * 32 + quad * 8 + j];
            make_afrag(av, ah, al);
            mfma1g(g.W2a, ks, w, lane, ah, al, acc);
        }
        #pragma unroll
        for (int r = 0; r < 4; r++)
            sB[(quad * 4 + r) * 68 + w * 16 + m] = acc[r];
    }
    __syncthreads();

    // Phase B: edge buckets (4/wave) -> sA
    {
        int dbase = bb * 16 + w * 4;
        int q0 = (dbase == 0) ? 0 : g.ends_e[dbase - 1];
        int e1 = g.ends_e[dbase], e2 = g.ends_e[dbase + 1];
        int e3 = g.ends_e[dbase + 2], q1 = g.ends_e[dbase + 3];
        if (q0 < 0) q0 = 0; if (q0 > N_EDGES) q0 = N_EDGES;
        if (q1 < q0) q1 = q0; if (q1 > N_EDGES) q1 = N_EDGES;
        if (e1 < q0) e1 = q0; if (e1 > q1) e1 = q1;
        if (e2 < e1) e2 = e1; if (e2 > q1) e2 = q1;
        if (e3 < e2) e3 = e2; if (e3 > q1) e3 = q1;
        float ad0 = sB[(w * 4 + 0) * 68 + lane];
        float ad1 = sB[(w * 4 + 1) * 68 + lane];
        float ad2 = sB[(w * 4 + 2) * 68 + lane];
        float ad3 = sB[(w * 4 + 3) * 68 + lane];
        float s0 = 0.f, s1 = 0.f, s2 = 0.f, s3 = 0.f;
        for (int p = q0; p < q1; p += 8) {
            int ss[8]; float hv[8];
            #pragma unroll
            for (int i = 0; i < 8; i++) {
                int sv = (p + i < q1) ? g.src_s[p + i] : 0;
                if ((unsigned)sv >= N_NODES) sv = 0;
                ss[i] = sv;
            }
            #pragma unroll
            for (int i = 0; i < 8; i++)
                hv[i] = g.Y[(size_t)ss[i] * 64 + lane];
            #pragma unroll
            for (int i = 0; i < 8; i++) {
                int pp = p + i;
                if (pp >= q1) continue;
                float ad = (pp >= e3) ? ad3 : (pp >= e2) ? ad2 : (pp >= e1) ? ad1 : ad0;
                float v = fmaxf(hv[i] + ad, 0.f);
                if (pp < e1) s0 += v;
                else if (pp < e2) s1 += v;
                else if (pp < e3) s2 += v;
                else s3 += v;
            }
        }
        sA[(w * 4 + 0) * 68 + lane] = s0;
        sA[(w * 4 + 1) * 68 + lane] = s1;
        sA[(w * 4 + 2) * 68 + lane] = s2;
        sA[(w * 4 + 3) * 68 + lane] = s3;
    }
    __syncthreads();

    // Phase C1: z = relu([A1 | aggr] @ Wn1 + bn1) -> sB
    {
        float b = g.bn1l[w * 16 + m];
        f4v acc = (f4v){b, b, b, b};
        #pragma unroll
        for (int ks = 0; ks < 2; ks++) {
            ldrow8f(g.A1, row, ks, quad, av);
            make_afrag(av, ah, al);
            mfma1g(g.Wn1l, ks, w, lane, ah, al, acc);
        }
        #pragma unroll
        for (int ks = 0; ks < 2; ks++) {
            #pragma unroll
            for (int j = 0; j < 8; j++)
                av[j] = sA[m * 68 + ks * 32 + quad * 8 + j];
            make_afrag(av, ah, al);
            mfma1g(g.Wn1l + 64 * 64, ks, w, lane, ah, al, acc);
        }
        #pragma unroll
        for (int r = 0; r < 4; r++)
            sB[(quad * 4 + r) * 68 + w * 16 + m] = fmaxf(acc[r], 0.f);
    }
    __syncthreads();

    // Phase C2: h' = z @ Wn2 + bn2 -> global (+ next XY)
    f4v acc2;
    {
        float b = g.bn2l[w * 16 + m];
        acc2 = (f4v){b, b, b, b};
        #pragma unroll
        for (int ks = 0; ks < 2; ks++) {
            #pragma unroll
            for (int j = 0; j < 8; j++)
                av[j] = sB[m * 68 + ks * 32 + quad * 8 + j];
            make_afrag(av, ah, al);
            mfma1g(g.Wn2l, ks, w, lane, ah, al, acc2);
        }
        #pragma unroll
        for (int r = 0; r < 4; r++)
            NTS(&g.hout[(size_t)(bb * 16 + quad * 4 + r) * 64 + w * 16 + m], acc2[r]);
    }
    if (g.has_next) {
        __syncthreads();
        #pragma unroll
        for (int r = 0; r < 4; r++)
            sA[(quad * 4 + r) * 68 + w * 16 + m] = acc2[r];
        __syncthreads();
        float bx = g.b1n[w * 16 + m];
        float by = g.b2n[w * 16 + m];
        f4v aX = (f4v){bx, bx, bx, bx};
        f4v aY = (f4v){by, by, by, by};
        #pragma unroll
        for (int ks = 0; ks < 2; ks++) {
            #pragma unroll
            for (int j = 0; j < 8; j++)
                av[j] = sA[m * 68 + ks * 32 + quad * 8 + j];
            make_afrag(av, ah, al);
            mfma1g(g.W1n, ks, w, lane, ah, al, aX);
            mfma1g(g.W2n, ks, w, lane, ah, al, aY);
        }
        #pragma unroll
        for (int r = 0; r < 4; r++) {
            size_t rr = (size_t)(bb * 16 + quad * 4 + r) * 64 + w * 16 + m;
            NTS(&g.Xn[rr], aX[r]);
            NTS(&g.Yn[rr], aY[r]);
        }
    }
}

__device__ void lin2out_tile(const float* x, const float* W1, const float* b1,
                             const float* W2, const float* b2,
                             float* X, float* Y, int tile) {
    const int lane = threadIdx.x & 63;
    const int w = threadIdx.x >> 6;
    const int quad = lane >> 4;
    const int m = lane & 15;
    size_t row = (size_t)tile * 16 + m;
    float bx = b1[w * 16 + m];
    float by = b2[w * 16 + m];
    f4v aX = (f4v){bx, bx, bx, bx};
    f4v aY = (f4v){by, by, by, by};
    float av[8]; s8v ah, al;
    #pragma unroll
    for (int ks = 0; ks < 2; ks++) {
        ldrow8f(x, row, ks, quad, av);
        make_afrag(av, ah, al);
        mfma1g(W1, ks, w, lane, ah, al, aX);
        mfma1g(W2, ks, w, lane, ah, al, aY);
    }
    #pragma unroll
    for (int r = 0; r < 4; r++) {
        size_t rr = (size_t)(tile * 16 + quad * 4 + r) * 64 + w * 16 + m;
        NTS(&X[rr], aX[r]);
        NTS(&Y[rr], aY[r]);
    }
}

// ---------------------------------------------------------------- diag
__global__ void k_fill(float* __restrict__ out, float val, int n) {
    int i = blockIdx.x * blockDim.x + threadIdx.x;
    if (i < n) out[i] = val;
}

// ---------------------------------------------------------------- setup kernels
__global__ void k_setup(int* __restrict__ cur) {
    int i = blockIdx.x * blockDim.x + threadIdx.x;
    int stride = gridDim.x * blockDim.x;
    for (; i < 2 * N_NODES; i += stride) cur[i] = 0;
}

__global__ void k_hist2(const int* __restrict__ j_idx, const int* __restrict__ edge_index,
                        int* __restrict__ cur_t, int* __restrict__ cur_e) {
    const int TB = (N_TRI + 255) / 256;
    if ((int)blockIdx.x < TB) {
        int i = blockIdx.x * 256 + threadIdx.x;
        if (i < N_TRI) {
            unsigned j = (unsigned)j_idx[i];
            if (j < N_NODES) atomicAdd(&cur_t[j], 1);
        }
    } else {
        int i = (blockIdx.x - TB) * 256 + threadIdx.x;
        if (i < N_EDGES) {
            unsigned d = (unsigned)edge_index[N_EDGES + i];
            if (d < N_NODES) atomicAdd(&cur_e[d], 1);
        }
    }
}

__global__ __launch_bounds__(256) void k_scan2(int* __restrict__ a, int* __restrict__ b) {
    int* cnt = (blockIdx.x == 0) ? a : b;
    __shared__ int part[256];
    int tid = threadIdx.x;
    const int PER = (N_NODES + 255) / 256;
    int base = tid * PER;
    int s = 0;
    for (int i = 0; i < PER; i++) {
        int idx = base + i;
        if (idx < N_NODES) s += cnt[idx];
    }
    part[tid] = s;
    __syncthreads();
    for (int d = 1; d < 256; d <<= 1) {
        int v = (tid >= d) ? part[tid - d] : 0;
        __syncthreads();
        part[tid] += v;
        __syncthreads();
    }
    int run = (tid > 0) ? part[tid - 1] : 0;
    for (int i = 0; i < PER; i++) {
        int idx = base + i;
        if (idx < N_NODES) {
            int v = cnt[idx];
            cnt[idx] = run;
            run += v;
        }
    }
}

// merged scatter (blocks [0, TB+EB)) + layer-0 lin2out (blocks [TB+EB, TB+EB+NTILE))
__global__ __launch_bounds__(256) void k_scatlin(
    const int* __restrict__ j_idx, const int* __restrict__ k_idx,
    const int* __restrict__ edge_index,
    int* __restrict__ cur_t, int* __restrict__ cur_e,
    int* __restrict__ tri_o, int* __restrict__ k_srt, int* __restrict__ src_s,
    const float* __restrict__ x,
    const float* __restrict__ W1, const float* __restrict__ b1,
    const float* __restrict__ W2, const float* __restrict__ b2,
    float* __restrict__ X, float* __restrict__ Y) {
    const int TB = (N_TRI + 255) / 256;   // 2500
    const int EB = (N_EDGES + 255) / 256; // 1000
    int bid = blockIdx.x;
    if (bid < TB) {
        int i = bid * 256 + threadIdx.x;
        if (i < N_TRI) {
            unsigned j = (unsigned)j_idx[i];
            if (j < N_NODES) {
                int pos = atomicAdd(&cur_t[j], 1);
                if ((unsigned)pos < (unsigned)N_TRI) {
                    unsigned k = (unsigned)k_idx[i]; if (k >= N_NODES) k = 0;
                    tri_o[pos] = i;
                    k_srt[pos] = (int)k;
                }
            }
        }
    } else if (bid < TB + EB) {
        int e = (bid - TB) * 256 + threadIdx.x;
        if (e < N_EDGES) {
            unsigned d = (unsigned)edge_index[N_EDGES + e];
            if (d < N_NODES) {
                int pos = atomicAdd(&cur_e[d], 1);
                if ((unsigned)pos < (unsigned)N_EDGES) {
                    unsigned s = (unsigned)edge_index[e]; if (s >= N_NODES) s = 0;
                    src_s[pos] = (int)s;
                }
            }
        }
    } else {
        lin2out_tile(x, W1, b1, W2, b2, X, Y, bid - TB - EB);
    }
    // cursors now hold bucket END offsets
}

__global__ __launch_bounds__(256) void k_meg(LayerP g) {
    __shared__ float sA[16 * 68];
    __shared__ float sB[16 * 68];
    meg_tile(g, blockIdx.x, sA, sB);
}

__global__ __launch_bounds__(256) void k_poolhead(
    const float* __restrict__ h, const int* __restrict__ batch,
    const float* __restrict__ Wo1, const float* __restrict__ bo1,
    const float* __restrict__ Wo2, const float* __restrict__ bo2,
    float* __restrict__ out) {
    __shared__ float red[4 * 64];
    const int lane = threadIdx.x & 63;
    const int w = threadIdx.x >> 6;
    int b = blockIdx.x;
    int lo = 0, hi = N_NODES;
    while (lo < hi) { int mid = (lo + hi) >> 1; if (batch[mid] < b) lo = mid + 1; else hi = mid; }
    int start = lo;
    hi = N_NODES;
    while (lo < hi) { int mid = (lo + hi) >> 1; if (batch[mid] < b + 1) lo = mid + 1; else hi = mid; }
    int end = lo;
    float s = 0.f;
    for (int n = start + w; n < end; n += 4)
        s += h[(size_t)n * 64 + lane];
    red[w * 64 + lane] = s;
    __syncthreads();
    if (w == 0) {
        float tot = red[lane] + red[64 + lane] + red[128 + lane] + red[192 + lane];
        float c = (float)(end - start);
        float p = fmaxf(tot / fmaxf(c, 1.0f), 0.f);
        float acc = bo1[lane];
        #pragma unroll
        for (int kk = 0; kk < 64; kk++)
            acc += __shfl(p, kk) * Wo1[kk * 64 + lane];
        float t1 = fmaxf(acc, 0.f);
        float acc2 = (lane < OUT_DIM) ? bo2[lane] : 0.f;
        #pragma unroll
        for (int kk = 0; kk < 64; kk++) {
            float wv = (lane < OUT_DIM) ? Wo2[kk * OUT_DIM + lane] : 0.f;
            acc2 += __shfl(t1, kk) * wv;
        }
        if (lane < OUT_DIM) out[b * OUT_DIM + lane] = acc2;
    }
}

extern "C" void kernel_launch(void* const* d_in, const int* in_sizes, int n_in,
                              void* d_out, int out_size, void* d_ws, size_t ws_size,
                              hipStream_t stream) {
    const int expect[19] = {
        N_NODES * 64, N_EDGES * 6, N_TRI * 6,
        L_LAYERS * 76 * 64, L_LAYERS * 64,
        L_LAYERS * 128 * 64, L_LAYERS * 64,
        L_LAYERS * 128 * 64, L_LAYERS * 64,
        L_LAYERS * 64 * 64, L_LAYERS * 64,
        64 * 64, 64, 64 * OUT_DIM, OUT_DIM,
        2 * N_EDGES, N_TRI, N_TRI, N_NODES
    };

    char* ws = (char*)d_ws;
    float* hA    = (float*)(ws + 0);
    float* hB    = (float*)(ws + 4096000);
    float* X0    = (float*)(ws + 8192000);
    float* Y0    = (float*)(ws + 12288000);
    float* X1    = (float*)(ws + 16384000);
    float* Y1    = (float*)(ws + 20480000);
    int*   cur_t = (int*)(ws + 24576000);
    int*   cur_e = (int*)(ws + 24640000);
    int*   tri_o = (int*)(ws + 24704000);
    int*   k_srt = (int*)(ws + 27264000);
    int*   src_s = (int*)(ws + 29824000);
    const size_t FULL_NEED = 30848000u;

    const int out_n = N_B * OUT_DIM;

    int perm[19];
    bool used[64];
    for (int i = 0; i < 64; i++) used[i] = false;
    int fail_slot = -1;
    for (int i = 0; i < 19; i++) {
        perm[i] = -1;
        for (int jj = 0; jj < n_in && jj < 64; jj++) {
            if (!used[jj] && in_sizes[jj] == expect[i]) { used[jj] = true; perm[i] = jj; break; }
        }
        if (perm[i] < 0 && fail_slot < 0) fail_slot = i;
    }

    if (n_in < 19 || fail_slot >= 0 || ws_size < FULL_NEED) {
        float code = (ws_size < FULL_NEED) ? 40000.0f
                   : (n_in < 19)           ? 50000.0f
                   : 20000.0f + 1000.0f * (float)fail_slot;
        k_fill<<<(out_n + 255) / 256, 256, 0, stream>>>((float*)d_out, code, out_n);
        return;
    }

    const float* x    = (const float*)d_in[perm[0]];
    const float* rbf  = (const float*)d_in[perm[1]];
    const float* cbf  = (const float*)d_in[perm[2]];
    const float* W1   = (const float*)d_in[perm[3]];
    const float* b1   = (const float*)d_in[perm[4]];
    const float* W2   = (const float*)d_in[perm[5]];
    const float* b2   = (const float*)d_in[perm[6]];
    const float* Wn1  = (const float*)d_in[perm[7]];
    const float* bn1  = (const float*)d_in[perm[8]];
    const float* Wn2  = (const float*)d_in[perm[9]];
    const float* bn2  = (const float*)d_in[perm[10]];
    const float* Wo1  = (const float*)d_in[perm[11]];
    const float* bo1  = (const float*)d_in[perm[12]];
    const float* Wo2  = (const float*)d_in[perm[13]];
    const float* bo2  = (const float*)d_in[perm[14]];
    const int* edge_index = (const int*)d_in[perm[15]];
    const int* k_idx = (const int*)d_in[perm[16]];
    const int* j_idx = (const int*)d_in[perm[17]];
    const int* batch = (const int*)d_in[perm[18]];

    const int TB = (N_TRI + 255) / 256;    // 2500
    const int EB = (N_EDGES + 255) / 256;  // 1000
    const int NTILE = N_NODES / 16;        // 1000

    // ---- 8 dispatches ----
    k_setup<<<64, 256, 0, stream>>>(cur_t);
    k_hist2<<<TB + EB, 256, 0, stream>>>(j_idx, edge_index, cur_t, cur_e);
    k_scan2<<<2, 256, 0, stream>>>(cur_t, cur_e);
    // scatter + layer-0 lin2out merged (independent work)
    k_scatlin<<<TB + EB + NTILE, 256, 0, stream>>>(j_idx, k_idx, edge_index,
                                                   cur_t, cur_e, tri_o, k_srt, src_s,
                                                   x, W1, b1, W2, b2, X0, Y0);

    const float* hc = x;
    float* hout = hA;
    float* Xc = X0; float* Yc = Y0;
    float* Xn = X1; float* Yn = Y1;
    for (int l = 0; l < L_LAYERS; l++) {
        LayerP g;
        g.ends_t = cur_t; g.tri_o = tri_o; g.k_srt = k_srt;
        g.ends_e = cur_e; g.src_s = src_s;
        g.X = Xc; g.Y = Yc;
        g.rbf = rbf; g.cbf = cbf; g.A1 = hc;
        g.W1l  = W1 + (size_t)l * 76 * 64;
        g.W2a  = W2 + (size_t)l * 128 * 64 + 64 * 64;
        g.Wn1l = Wn1 + (size_t)l * 128 * 64;
        g.bn1l = bn1 + (size_t)l * 64;
        g.Wn2l = Wn2 + (size_t)l * 64 * 64;
        g.bn2l = bn2 + (size_t)l * 64;
        g.has_next = (l < L_LAYERS - 1) ? 1 : 0;
        g.W1n = W1 + (size_t)(l + 1) * 76 * 64;
        g.b1n = b1 + (size_t)(l + 1) * 64;
        g.W2n = W2 + (size_t)(l + 1) * 128 * 64;
        g.b2n = b2 + (size_t)(l + 1) * 64;
        g.hout = hout; g.Xn = Xn; g.Yn = Yn;
        k_meg<<<NTILE, 256, 0, stream>>>(g);
        hc = hout;
        hout = (hout == hA) ? hB : hA;
        float* t;
        t = Xc; Xc = Xn; Xn = t;
        t = Yc; Yc = Yn; Yn = t;
    }
    k_poolhead<<<N_B, 256, 0, stream>>>(hA, batch, Wo1, bo1, Wo2, bo2, (float*)d_out);
}